// Round 8
// baseline (185.485 us; speedup 1.0000x reference)
//
#include <hip/hip_runtime.h>
#include <stdint.h>

#define S_LEN 2048
#define BATCH 2
#define EMB   1024
#define NHEAD 16
#define HDIM  64

typedef __bf16 bf8   __attribute__((ext_vector_type(8)));
typedef float  f32x4 __attribute__((ext_vector_type(4)));
typedef float  f32x16 __attribute__((ext_vector_type(16)));

__device__ __forceinline__ unsigned short f2bf(float f) {
    unsigned u = __builtin_bit_cast(unsigned, f);
    u += 0x7fffu + ((u >> 16) & 1u);          // round-to-nearest-even
    return (unsigned short)(u >> 16);
}
__device__ __forceinline__ float bf2f(unsigned short h) {
    unsigned u = ((unsigned)h) << 16;
    return __builtin_bit_cast(float, u);
}

__device__ __forceinline__ void gl_lds16(const unsigned short* g, unsigned short* l) {
    __builtin_amdgcn_global_load_lds(
        (__attribute__((address_space(1))) void*)(void*)g,
        (__attribute__((address_space(3))) void*)(void*)l, 16, 0, 0);
}

// ---------------- rope tables: cos/sin [S][64] fp32 ----------------
__global__ void k_tables(float* __restrict__ cosT, float* __restrict__ sinT) {
    int idx = blockIdx.x * 256 + threadIdx.x;   // 2048*64 = 131072
    int s = idx >> 6, d = idx & 63, j = d & 31;
    float inv = exp2f(-13.28771237954945f * ((float)j * (1.0f / 32.0f))); // 10000^(-j/32)
    float ang = (float)s * inv;
    cosT[idx] = cosf(ang);
    sinT[idx] = sinf(ang);
}

// ---------------- cast query [S,B,E] f32 -> xb [B,S,E] bf16 ----------------
__global__ void k_cast_x(const float* __restrict__ x, unsigned short* __restrict__ xb) {
    int id = blockIdx.x * 256 + threadIdx.x;    // 1048576 (4 elems each)
    int b = id >> 19, rem = id & 524287;
    int s = rem >> 8, e4 = (rem & 255) << 2;
    float4 v = *(const float4*)&x[((size_t)(s * BATCH + b)) * EMB + e4];
    ushort4 o;
    o.x = f2bf(v.x); o.y = f2bf(v.y); o.z = f2bf(v.z); o.w = f2bf(v.w);
    *(ushort4*)&xb[((size_t)(b * S_LEN + s)) * EMB + e4] = o;
}

// ---------------- all four weight casts in one launch ----------------
__global__ void k_castW(const float* __restrict__ w0, const float* __restrict__ w1,
                        const float* __restrict__ w2, const float* __restrict__ w3,
                        unsigned short* __restrict__ o0, unsigned short* __restrict__ o1,
                        unsigned short* __restrict__ o2, unsigned short* __restrict__ o3) {
    int id = blockIdx.x * 256 + threadIdx.x;    // 4 segments * 262144
    int seg = id >> 18, r = id & 262143;
    const float* s = seg == 0 ? w0 : seg == 1 ? w1 : seg == 2 ? w2 : w3;
    unsigned short* o = seg == 0 ? o0 : seg == 1 ? o1 : seg == 2 ? o2 : o3;
    float4 v = *(const float4*)&s[(size_t)r * 4];
    ushort4 u;
    u.x = f2bf(v.x); u.y = f2bf(v.y); u.z = f2bf(v.z); u.w = f2bf(v.w);
    *(ushort4*)&o[(size_t)r * 4] = u;
}

// ---------------- merged QKV GEMM, rope fused into q/k epilogues ----------------
// grid (8, 32, 3). z=0: q (rope, pre-scaled by 0.125*log2e). z=1: k (rope).
// z=2: v, written TRANSPOSED to vT[f][m] (+bias).
__global__ void __launch_bounds__(256) k_gemmQKV(
    const unsigned short* __restrict__ A,
    const unsigned short* __restrict__ Wq, const unsigned short* __restrict__ Wk,
    const unsigned short* __restrict__ Wv,
    const float* __restrict__ bqp, const float* __restrict__ bkp, const float* __restrict__ bvp,
    unsigned short* __restrict__ qout, unsigned short* __restrict__ kout,
    unsigned short* __restrict__ vout,
    const float* __restrict__ cosT, const float* __restrict__ sinT)
{
    __shared__ __align__(16) unsigned short As[128 * 32];
    __shared__ __align__(16) unsigned short Bs[128 * 32];
    const int z = blockIdx.z;
    const unsigned short* B = z == 0 ? Wq : z == 1 ? Wk : Wv;
    const float* bias = z == 0 ? bqp : z == 1 ? bkp : bvp;
    const int tid  = threadIdx.x;
    const int lane = tid & 63;
    const int wid  = tid >> 6;
    const int wm = wid >> 1, wn = wid & 1;
    const int l15 = lane & 15, lh = lane >> 4;
    const int tm0 = blockIdx.y * 128, tn0 = blockIdx.x * 128;
    const int K = 1024;

    f32x4 acc[4][4] = {};

    for (int k0 = 0; k0 < K; k0 += 32) {
        __syncthreads();
#pragma unroll
        for (int rnd = 0; rnd < 2; ++rnd) {
            int cbase = wid * 64 + rnd * 256;          // wave-uniform chunk base
            int c = cbase + lane;
            int row = c >> 2, co = (c & 3) * 8;
            gl_lds16(A + (size_t)(tm0 + row) * K + k0 + co, &As[cbase * 8]);
            gl_lds16(B + (size_t)(tn0 + row) * K + k0 + co, &Bs[cbase * 8]);
        }
        __syncthreads();
        bf8 a[4], b[4];
#pragma unroll
        for (int i = 0; i < 4; ++i) {
            a[i] = *(const bf8*)&As[(wm * 64 + i * 16 + l15) * 32 + lh * 8];
            b[i] = *(const bf8*)&Bs[(wn * 64 + i * 16 + l15) * 32 + lh * 8];
        }
#pragma unroll
        for (int i = 0; i < 4; ++i)
#pragma unroll
            for (int j = 0; j < 4; ++j)
                acc[i][j] = __builtin_amdgcn_mfma_f32_16x16x32_bf16(a[i], b[j], acc[i][j], 0, 0, 0);
    }

    if (z < 2) {
        unsigned short* C = z ? kout : qout;
        const float f = z ? 1.0f : 0.125f * 1.44269504089f;
#pragma unroll
        for (int i = 0; i < 4; ++i) {
            const int rowb = tm0 + wm * 64 + i * 16 + lh * 4;
#pragma unroll
            for (int j = 0; j < 2; ++j) {
                const int col = tn0 + wn * 64 + j * 16 + l15;   // d = j*16+l15 in [0,32)
                const int d = j * 16 + l15;
#pragma unroll
                for (int r = 0; r < 4; ++r) {
                    int m = rowb + r;
                    int sq = m & (S_LEN - 1);
                    float x1 = acc[i][j][r]     + bias[col];
                    float x2 = acc[i][j + 2][r] + bias[col + 32];
                    float c  = cosT[sq * 64 + d] * f;
                    float sn = sinT[sq * 64 + d] * f;
                    C[(size_t)m * EMB + col]      = f2bf(x1 * c - x2 * sn);
                    C[(size_t)m * EMB + col + 32] = f2bf(x2 * c + x1 * sn);
                }
            }
        }
    } else {
#pragma unroll
        for (int i = 0; i < 4; ++i) {
            const int rowb = tm0 + wm * 64 + i * 16 + lh * 4;
#pragma unroll
            for (int j = 0; j < 4; ++j) {
                const int col = tn0 + wn * 64 + j * 16 + l15;
                float bv = bias[col];
#pragma unroll
                for (int r = 0; r < 4; ++r)
                    vout[(size_t)col * 4096 + rowb + r] = f2bf(acc[i][j][r] + bv);
            }
        }
    }
}

// ---------------- flash attention, 3-buffer pipelined LDS staging, KV-split=2 ----------------
// grid: (S/128, B*H, 2). 4 waves/block; wave owns 32 q rows x 1024 KV positions.
// T3/T4: stage issued 2 chunks ahead into a 3-deep LDS ring; ONE raw s_barrier per
// chunk preceded by counted s_waitcnt vmcnt(4) (vmcnt(0) only on the last chunk).
// Safety: stage(t+2) targets the buffer last read in chunk t-1, and is issued only
// after barrier t (all waves' t-1 ds_reads completed before their barrier arrival).
__global__ void __launch_bounds__(256) k_attn7(
    const unsigned short* __restrict__ qb,
    const unsigned short* __restrict__ kb,
    const unsigned short* __restrict__ vT,
    float* __restrict__ po0, float* __restrict__ po1,
    float* __restrict__ ml)
{
    __shared__ __align__(16) unsigned short Kl[3][4096];   // [64 rows][64 shorts] x3
    __shared__ __align__(16) unsigned short Vl[3][4096];
    __shared__ float bl[4][32];
    const int tid = threadIdx.x, lane = tid & 63, wid = tid >> 6;
    const int l31 = lane & 31, hi = lane >> 5;
    const int bh = blockIdx.y;
    const int b = bh >> 4, h = bh & 15;
    const int z = blockIdx.z;
    const int kv0 = z << 10;                 // 1024 KV per half
    const int q0 = blockIdx.x * 128 + wid * 32;
    float* __restrict__ po = z ? po1 : po0;
    float* __restrict__ mlz = ml + (size_t)z * (32 * 2048 * 2);

    const unsigned short* qrow = qb + ((size_t)(b * S_LEN + q0 + l31)) * EMB + h * HDIM + hi * 8;
    bf8 qf[4];
#pragma unroll
    for (int c = 0; c < 4; ++c) qf[c] = *(const bf8*)(qrow + c * 16);

    // staging bases (shorts)
    const unsigned short* kb_g = kb + (size_t)b * S_LEN * EMB + h * HDIM;
    const unsigned short* vT_g = vT + (size_t)h * HDIM * (S_LEN * BATCH) + b * S_LEN;

    const int srow = lane >> 3;          // 0..7 within 8-row sub-block
    const int sp   = lane & 7;           // 16B slot 0..7
    auto stage = [&](int buf, int j0) {
#pragma unroll
        for (int i = 0; i < 2; ++i) {
            int blk = wid * 2 + i;                   // 1KB sub-block 0..7
            int r = blk * 8 + srow;                  // tile row 0..63
            int ps = sp ^ (r & 7);                   // swizzled global slot
            gl_lds16(kb_g + (size_t)(j0 + r) * EMB + ps * 8, &Kl[buf][blk * 512]);
            gl_lds16(vT_g + (size_t)r * (S_LEN * BATCH) + j0 + ps * 8, &Vl[buf][blk * 512]);
        }
    };

    auto pack2 = [](float lo, float hh) -> unsigned {
        unsigned short a  = __builtin_bit_cast(unsigned short, (__bf16)lo);
        unsigned short bb = __builtin_bit_cast(unsigned short, (__bf16)hh);
        return ((unsigned)bb << 16) | a;
    };

    float m_run = 0.f, l_run = 0.f;
    f32x16 oacc0 = {}, oacc1 = {};

    const int rA = l31, rB = 32 + l31;

    const int NT = 1024 / 64;            // 16 chunks
    stage(0, kv0);
    stage(1, kv0 + 64);
    int cur = 0;

    for (int t = 0; t < NT; ++t) {
        // counted wait: own chunk-t loads landed; t+1's may stay in flight (T4)
        if (t < NT - 1) asm volatile("s_waitcnt vmcnt(4)" ::: "memory");
        else            asm volatile("s_waitcnt vmcnt(0)" ::: "memory");
        __builtin_amdgcn_s_barrier();

        // issue stage for chunk t+2 (buffer last read in chunk t-1 -> safe now)
        if (t + 2 < NT) {
            int nb = cur + 2; if (nb >= 3) nb -= 3;
            stage(nb, kv0 + (t + 2) * 64);
        }

        // ---- QK^T from LDS: two independent chains ----
        f32x16 stA = {}, stB = {};
        __builtin_amdgcn_s_setprio(1);
#pragma unroll
        for (int c = 0; c < 4; ++c) {
            int s = c * 2 + hi;
            bf8 kfa = *(const bf8*)&Kl[cur][rA * 64 + (s ^ (rA & 7)) * 8];
            bf8 kfb = *(const bf8*)&Kl[cur][rB * 64 + (s ^ (rB & 7)) * 8];
            stA = __builtin_amdgcn_mfma_f32_32x32x16_bf16(kfa, qf[c], stA, 0, 0, 0);
            stB = __builtin_amdgcn_mfma_f32_32x32x16_bf16(kfb, qf[c], stB, 0, 0, 0);
        }
        __builtin_amdgcn_s_setprio(0);
        // ---- max, balanced tree ----
        float mx[8];
#pragma unroll
        for (int i = 0; i < 8; ++i)
            mx[i] = fmaxf(fmaxf(stA[i], stA[i + 8]), fmaxf(stB[i], stB[i + 8]));
        float t0 = fmaxf(mx[0], mx[4]), t1 = fmaxf(mx[1], mx[5]);
        float t2 = fmaxf(mx[2], mx[6]), t3 = fmaxf(mx[3], mx[7]);
        float pmax = fmaxf(fmaxf(t0, t1), fmaxf(t2, t3));
        pmax = fmaxf(pmax, __shfl_xor(pmax, 32));
        if (!__all(pmax - m_run <= 11.54f)) {       // rare rescale path (defer-max)
            float mnew = fmaxf(m_run, pmax);
            float corr = exp2f(m_run - mnew);
            l_run *= corr;
            m_run = mnew;
            if (hi == 0) bl[wid][l31] = corr;
            asm volatile("s_waitcnt lgkmcnt(0)" ::: "memory");
#pragma unroll
            for (int r = 0; r < 16; ++r) {
                float c2 = bl[wid][(r & 3) + 8 * (r >> 2) + 4 * hi];
                oacc0[r] *= c2;
                oacc1[r] *= c2;
            }
        }
        // ---- chunk A: exp2, sum tree, pack ----
        float pA[16];
#pragma unroll
        for (int r = 0; r < 16; ++r) pA[r] = exp2f(stA[r] - m_run);
        float sA = ((pA[0] + pA[1]) + (pA[2] + pA[3])) + ((pA[4] + pA[5]) + (pA[6] + pA[7]));
        float sA2 = ((pA[8] + pA[9]) + (pA[10] + pA[11])) + ((pA[12] + pA[13]) + (pA[14] + pA[15]));
        unsigned a01 = pack2(pA[0], pA[1]),   a23 = pack2(pA[2], pA[3]);
        unsigned a45 = pack2(pA[4], pA[5]),   a67 = pack2(pA[6], pA[7]);
        unsigned a89 = pack2(pA[8], pA[9]),   aab = pack2(pA[10], pA[11]);
        unsigned acd = pack2(pA[12], pA[13]), aef = pack2(pA[14], pA[15]);
        unsigned rA_ = (unsigned)__shfl_xor((int)(hi ? a01 : a45), 32);
        unsigned rB_ = (unsigned)__shfl_xor((int)(hi ? a23 : a67), 32);
        unsigned rC_ = (unsigned)__shfl_xor((int)(hi ? a89 : acd), 32);
        unsigned rD_ = (unsigned)__shfl_xor((int)(hi ? aab : aef), 32);
        uint4 u0 = hi ? uint4{rA_, rB_, a45, a67} : uint4{a01, a23, rA_, rB_};
        uint4 u1 = hi ? uint4{rC_, rD_, acd, aef} : uint4{a89, aab, rC_, rD_};
        bf8 pf0A = __builtin_bit_cast(bf8, u0);
        bf8 pf1A = __builtin_bit_cast(bf8, u1);
        // ---- chunk B ----
        float pB[16];
#pragma unroll
        for (int r = 0; r < 16; ++r) pB[r] = exp2f(stB[r] - m_run);
        float sB = ((pB[0] + pB[1]) + (pB[2] + pB[3])) + ((pB[4] + pB[5]) + (pB[6] + pB[7]));
        float sB2 = ((pB[8] + pB[9]) + (pB[10] + pB[11])) + ((pB[12] + pB[13]) + (pB[14] + pB[15]));
        unsigned b01 = pack2(pB[0], pB[1]),   b23 = pack2(pB[2], pB[3]);
        unsigned b45 = pack2(pB[4], pB[5]),   b67 = pack2(pB[6], pB[7]);
        unsigned b89 = pack2(pB[8], pB[9]),   bab = pack2(pB[10], pB[11]);
        unsigned bcd = pack2(pB[12], pB[13]), bef = pack2(pB[14], pB[15]);
        unsigned sA_ = (unsigned)__shfl_xor((int)(hi ? b01 : b45), 32);
        unsigned sB_ = (unsigned)__shfl_xor((int)(hi ? b23 : b67), 32);
        unsigned sC_ = (unsigned)__shfl_xor((int)(hi ? b89 : bcd), 32);
        unsigned sD_ = (unsigned)__shfl_xor((int)(hi ? bab : bef), 32);
        uint4 w0 = hi ? uint4{sA_, sB_, b45, b67} : uint4{b01, b23, sA_, sB_};
        uint4 w1 = hi ? uint4{sC_, sD_, bcd, bef} : uint4{b89, bab, sC_, sD_};
        bf8 pf0B = __builtin_bit_cast(bf8, w0);
        bf8 pf1B = __builtin_bit_cast(bf8, w1);

        float psum = (sA + sA2) + (sB + sB2);
        psum += __shfl_xor(psum, 32);
        l_run += psum;

        // ---- PV from LDS V-tile ----
        __builtin_amdgcn_s_setprio(1);
#pragma unroll
        for (int c = 0; c < 4; ++c) {
            int s = c * 2 + hi;
            bf8 v0 = *(const bf8*)&Vl[cur][rA * 64 + (s ^ (rA & 7)) * 8];
            bf8 v1 = *(const bf8*)&Vl[cur][rB * 64 + (s ^ (rB & 7)) * 8];
            bf8 pf = (c == 0) ? pf0A : (c == 1) ? pf1A : (c == 2) ? pf0B : pf1B;
            oacc0 = __builtin_amdgcn_mfma_f32_32x32x16_bf16(pf, v0, oacc0, 0, 0, 0);
            oacc1 = __builtin_amdgcn_mfma_f32_32x32x16_bf16(pf, v1, oacc1, 0, 0, 0);
        }
        __builtin_amdgcn_s_setprio(0);

        cur = (cur == 2) ? 0 : cur + 1;
    }

    // ---- epilogue: store unnormalized fp32 partial O + (m,l) ----
#pragma unroll
    for (int r = 0; r < 16; ++r) {
        int q = (r & 3) + 8 * (r >> 2) + 4 * hi;
        size_t base = ((size_t)bh * 2048 + q0 + q) * 64 + l31;
        po[base]      = oacc0[r];
        po[base + 32] = oacc1[r];
    }
    if (hi == 0) {
        size_t mi = ((size_t)bh * 2048 + q0 + l31) * 2;
        mlz[mi]     = m_run;
        mlz[mi + 1] = l_run;
    }
}

// ---------------- combine the two KV halves -> ob bf16 [B,S,E] ----------------
__global__ void k_comb(const float* __restrict__ po0, const float* __restrict__ po1,
                       const float* __restrict__ ml, unsigned short* __restrict__ ob)
{
    int id = blockIdx.x * 256 + threadIdx.x;    // 32*2048*16 = 1048576
    int d4 = (id & 15) * 4;
    int q  = (id >> 4) & 2047;
    int bh = id >> 15;
    int b = bh >> 4, h = bh & 15;
    size_t mi = ((size_t)bh * 2048 + q) * 2;
    float m0 = ml[mi], l0 = ml[mi + 1];
    float m1 = ml[mi + (size_t)32 * 2048 * 2], l1 = ml[mi + (size_t)32 * 2048 * 2 + 1];
    float m = fmaxf(m0, m1);
    float w0 = exp2f(m0 - m), w1 = exp2f(m1 - m);
    float inv = 1.0f / (l0 * w0 + l1 * w1);
    size_t pi = ((size_t)bh * 2048 + q) * 64 + d4;
    float4 a = *(const float4*)&po0[pi];
    float4 c = *(const float4*)&po1[pi];
    ushort4 o;
    o.x = f2bf((a.x * w0 + c.x * w1) * inv);
    o.y = f2bf((a.y * w0 + c.y * w1) * inv);
    o.z = f2bf((a.z * w0 + c.z * w1) * inv);
    o.w = f2bf((a.w * w0 + c.w * w1) * inv);
    *(ushort4*)&ob[((size_t)(b * S_LEN + q)) * EMB + h * HDIM + d4] = o;
}

// ---------------- final GEMM (out fp32, row remap) ----------------
template<int EPI, typename OutT>
__global__ void __launch_bounds__(256) k_gemm(
    const unsigned short* __restrict__ A,
    const unsigned short* __restrict__ B,
    const float* __restrict__ bias,
    OutT* __restrict__ C,
    int M, int N, int K)
{
    __shared__ __align__(16) unsigned short As[128 * 32];
    __shared__ __align__(16) unsigned short Bs[128 * 32];
    const int tid  = threadIdx.x;
    const int lane = tid & 63;
    const int wid  = tid >> 6;
    const int wm = wid >> 1, wn = wid & 1;
    const int l15 = lane & 15, lh = lane >> 4;
    const int tm0 = blockIdx.y * 128, tn0 = blockIdx.x * 128;

    f32x4 acc[4][4] = {};

    for (int k0 = 0; k0 < K; k0 += 32) {
        __syncthreads();
#pragma unroll
        for (int rnd = 0; rnd < 2; ++rnd) {
            int cbase = wid * 64 + rnd * 256;
            int c = cbase + lane;
            int row = c >> 2, co = (c & 3) * 8;
            gl_lds16(A + (size_t)(tm0 + row) * K + k0 + co, &As[cbase * 8]);
            gl_lds16(B + (size_t)(tn0 + row) * K + k0 + co, &Bs[cbase * 8]);
        }
        __syncthreads();
        bf8 a[4], b[4];
#pragma unroll
        for (int i = 0; i < 4; ++i) {
            a[i] = *(const bf8*)&As[(wm * 64 + i * 16 + l15) * 32 + lh * 8];
            b[i] = *(const bf8*)&Bs[(wn * 64 + i * 16 + l15) * 32 + lh * 8];
        }
#pragma unroll
        for (int i = 0; i < 4; ++i)
#pragma unroll
            for (int j = 0; j < 4; ++j)
                acc[i][j] = __builtin_amdgcn_mfma_f32_16x16x32_bf16(a[i], b[j], acc[i][j], 0, 0, 0);
    }

#pragma unroll
    for (int i = 0; i < 4; ++i) {
        const int rowb = tm0 + wm * 64 + i * 16 + lh * 4;
#pragma unroll
        for (int j = 0; j < 4; ++j) {
            const int col = tn0 + wn * 64 + j * 16 + l15;
#pragma unroll
            for (int r = 0; r < 4; ++r) {
                float v = acc[i][j][r];
                int row = rowb + r;
                if (EPI == 0) {
                    v += bias[col];
                    C[(size_t)row * N + col] = (OutT)f2bf(v);
                } else {
                    v += bias[col];
                    int bb = row >> 11, ss = row & 2047;
                    ((float*)C)[(size_t)(ss * BATCH + bb) * N + col] = v;
                }
            }
        }
    }
}

extern "C" void kernel_launch(void* const* d_in, const int* in_sizes, int n_in,
                              void* d_out, int out_size, void* d_ws, size_t ws_size,
                              hipStream_t stream)
{
    (void)in_sizes; (void)n_in; (void)out_size; (void)ws_size;
    const float* query = (const float*)d_in[0];
    const float* wq = (const float*)d_in[1];
    const float* bq = (const float*)d_in[2];
    const float* wk = (const float*)d_in[3];
    const float* bk = (const float*)d_in[4];
    const float* wv = (const float*)d_in[5];
    const float* bv = (const float*)d_in[6];
    const float* wo = (const float*)d_in[7];
    const float* bo = (const float*)d_in[8];

    // ws layout, 59 MB peak:
    //  [0,1)    cosT/sinT  -> later ml
    //  [1,17)   xb/wqb/wkb/wvb -> later po0 fp32
    //  [17,25)  qb -> later ob
    //  [25,33)  kb
    //  [33,41)  vT
    //  [41,57)  po1 fp32
    //  [57,59)  wob
    char* ws = (char*)d_ws;
    float*          cosT = (float*)(ws + 0);
    float*          sinT = (float*)(ws + (512 << 10));
    float*          ml   = (float*)(ws + 0);
    unsigned short* xb   = (unsigned short*)(ws + (1  << 20));
    float*          po0  = (float*)(ws + (1  << 20));
    unsigned short* wqb  = (unsigned short*)(ws + (9  << 20));
    unsigned short* wkb  = (unsigned short*)(ws + (11 << 20));
    unsigned short* wvb  = (unsigned short*)(ws + (13 << 20));
    unsigned short* qb   = (unsigned short*)(ws + (17 << 20));
    unsigned short* ob   = qb;                                  // time-shared
    unsigned short* kb   = (unsigned short*)(ws + (25 << 20));
    unsigned short* vT   = (unsigned short*)(ws + (33 << 20));
    float*          po1  = (float*)(ws + (41 << 20));
    unsigned short* wob  = (unsigned short*)(ws + (57 << 20));

    k_tables<<<512, 256, 0, stream>>>(cosT, sinT);
    k_cast_x<<<4096, 256, 0, stream>>>(query, xb);
    k_castW<<<4096, 256, 0, stream>>>(wq, wk, wv, wo, wqb, wkb, wvb, wob);

    dim3 gq(EMB / 128, (S_LEN * BATCH) / 128, 3);    // (8, 32, 3)
    k_gemmQKV<<<gq, 256, 0, stream>>>(xb, wqb, wkb, wvb, bq, bk, bv,
                                      qb, kb, vT, cosT, sinT);

    dim3 g3(S_LEN / 128, BATCH * NHEAD, 2);          // (16, 32, 2)
    k_attn7<<<g3, 256, 0, stream>>>(qb, kb, vT, po0, po1, ml);
    k_comb<<<4096, 256, 0, stream>>>(po0, po1, ml, ob);

    dim3 g1(EMB / 128, (S_LEN * BATCH) / 128);       // (8, 32)
    k_gemm<1, float><<<g1, 256, 0, stream>>>(ob, wob, bo, (float*)d_out, 4096, 1024, 1024);
}

// Round 13
// 167.978 us; speedup vs baseline: 1.1042x; 1.1042x over previous
//
#include <hip/hip_runtime.h>
#include <stdint.h>

#define S_LEN 2048
#define BATCH 2
#define EMB   1024
#define NHEAD 16
#define HDIM  64

typedef __bf16 bf8   __attribute__((ext_vector_type(8)));
typedef float  f32x4 __attribute__((ext_vector_type(4)));
typedef float  f32x16 __attribute__((ext_vector_type(16)));

__device__ __forceinline__ unsigned short f2bf(float f) {
    unsigned u = __builtin_bit_cast(unsigned, f);
    u += 0x7fffu + ((u >> 16) & 1u);          // round-to-nearest-even
    return (unsigned short)(u >> 16);
}
__device__ __forceinline__ float bf2f(unsigned short h) {
    unsigned u = ((unsigned)h) << 16;
    return __builtin_bit_cast(float, u);
}
__device__ __forceinline__ float fexp2(float x) { return __builtin_amdgcn_exp2f(x); }
__device__ __forceinline__ float f3max(float a, float b, float c) { return fmaxf(fmaxf(a, b), c); }

__device__ __forceinline__ void gl_lds16(const unsigned short* g, unsigned short* l) {
    __builtin_amdgcn_global_load_lds(
        (__attribute__((address_space(1))) void*)(void*)g,
        (__attribute__((address_space(3))) void*)(void*)l, 16, 0, 0);
}

// ---------------- rope tables: cos/sin [S][64] fp32 ----------------
__global__ void k_tables(float* __restrict__ cosT, float* __restrict__ sinT) {
    int idx = blockIdx.x * 256 + threadIdx.x;   // 2048*64 = 131072
    int s = idx >> 6, d = idx & 63, j = d & 31;
    float inv = exp2f(-13.28771237954945f * ((float)j * (1.0f / 32.0f))); // 10000^(-j/32)
    float ang = (float)s * inv;
    cosT[idx] = cosf(ang);
    sinT[idx] = sinf(ang);
}

// ---------------- cast query [S,B,E] f32 -> xb [B,S,E] bf16 ----------------
__global__ void k_cast_x(const float* __restrict__ x, unsigned short* __restrict__ xb) {
    int id = blockIdx.x * 256 + threadIdx.x;    // 1048576 (4 elems each)
    int b = id >> 19, rem = id & 524287;
    int s = rem >> 8, e4 = (rem & 255) << 2;
    float4 v = *(const float4*)&x[((size_t)(s * BATCH + b)) * EMB + e4];
    ushort4 o;
    o.x = f2bf(v.x); o.y = f2bf(v.y); o.z = f2bf(v.z); o.w = f2bf(v.w);
    *(ushort4*)&xb[((size_t)(b * S_LEN + s)) * EMB + e4] = o;
}

// ---------------- all four weight casts in one launch ----------------
__global__ void k_castW(const float* __restrict__ w0, const float* __restrict__ w1,
                        const float* __restrict__ w2, const float* __restrict__ w3,
                        unsigned short* __restrict__ o0, unsigned short* __restrict__ o1,
                        unsigned short* __restrict__ o2, unsigned short* __restrict__ o3) {
    int id = blockIdx.x * 256 + threadIdx.x;    // 4 segments * 262144
    int seg = id >> 18, r = id & 262143;
    const float* s = seg == 0 ? w0 : seg == 1 ? w1 : seg == 2 ? w2 : w3;
    unsigned short* o = seg == 0 ? o0 : seg == 1 ? o1 : seg == 2 ? o2 : o3;
    float4 v = *(const float4*)&s[(size_t)r * 4];
    ushort4 u;
    u.x = f2bf(v.x); u.y = f2bf(v.y); u.z = f2bf(v.z); u.w = f2bf(v.w);
    *(ushort4*)&o[(size_t)r * 4] = u;
}

// ---------------- merged QKV GEMM, rope fused into q/k epilogues ----------------
__global__ void __launch_bounds__(256) k_gemmQKV(
    const unsigned short* __restrict__ A,
    const unsigned short* __restrict__ Wq, const unsigned short* __restrict__ Wk,
    const unsigned short* __restrict__ Wv,
    const float* __restrict__ bqp, const float* __restrict__ bkp, const float* __restrict__ bvp,
    unsigned short* __restrict__ qout, unsigned short* __restrict__ kout,
    unsigned short* __restrict__ vout,
    const float* __restrict__ cosT, const float* __restrict__ sinT)
{
    __shared__ __align__(16) unsigned short As[128 * 32];
    __shared__ __align__(16) unsigned short Bs[128 * 32];
    const int z = blockIdx.z;
    const unsigned short* B = z == 0 ? Wq : z == 1 ? Wk : Wv;
    const float* bias = z == 0 ? bqp : z == 1 ? bkp : bvp;
    const int tid  = threadIdx.x;
    const int lane = tid & 63;
    const int wid  = tid >> 6;
    const int wm = wid >> 1, wn = wid & 1;
    const int l15 = lane & 15, lh = lane >> 4;
    const int tm0 = blockIdx.y * 128, tn0 = blockIdx.x * 128;
    const int K = 1024;

    f32x4 acc[4][4] = {};

    for (int k0 = 0; k0 < K; k0 += 32) {
        __syncthreads();
#pragma unroll
        for (int rnd = 0; rnd < 2; ++rnd) {
            int cbase = wid * 64 + rnd * 256;          // wave-uniform chunk base
            int c = cbase + lane;
            int row = c >> 2, co = (c & 3) * 8;
            gl_lds16(A + (size_t)(tm0 + row) * K + k0 + co, &As[cbase * 8]);
            gl_lds16(B + (size_t)(tn0 + row) * K + k0 + co, &Bs[cbase * 8]);
        }
        __syncthreads();
        bf8 a[4], b[4];
#pragma unroll
        for (int i = 0; i < 4; ++i) {
            a[i] = *(const bf8*)&As[(wm * 64 + i * 16 + l15) * 32 + lh * 8];
            b[i] = *(const bf8*)&Bs[(wn * 64 + i * 16 + l15) * 32 + lh * 8];
        }
#pragma unroll
        for (int i = 0; i < 4; ++i)
#pragma unroll
            for (int j = 0; j < 4; ++j)
                acc[i][j] = __builtin_amdgcn_mfma_f32_16x16x32_bf16(a[i], b[j], acc[i][j], 0, 0, 0);
    }

    if (z < 2) {
        unsigned short* C = z ? kout : qout;
        const float f = z ? 1.0f : 0.125f * 1.44269504089f;
#pragma unroll
        for (int i = 0; i < 4; ++i) {
            const int rowb = tm0 + wm * 64 + i * 16 + lh * 4;
#pragma unroll
            for (int j = 0; j < 2; ++j) {
                const int col = tn0 + wn * 64 + j * 16 + l15;   // d = j*16+l15 in [0,32)
                const int d = j * 16 + l15;
#pragma unroll
                for (int r = 0; r < 4; ++r) {
                    int m = rowb + r;
                    int sq = m & (S_LEN - 1);
                    float x1 = acc[i][j][r]     + bias[col];
                    float x2 = acc[i][j + 2][r] + bias[col + 32];
                    float c  = cosT[sq * 64 + d] * f;
                    float sn = sinT[sq * 64 + d] * f;
                    C[(size_t)m * EMB + col]      = f2bf(x1 * c - x2 * sn);
                    C[(size_t)m * EMB + col + 32] = f2bf(x2 * c + x1 * sn);
                }
            }
        }
    } else {
#pragma unroll
        for (int i = 0; i < 4; ++i) {
            const int rowb = tm0 + wm * 64 + i * 16 + lh * 4;
#pragma unroll
            for (int j = 0; j < 4; ++j) {
                const int col = tn0 + wn * 64 + j * 16 + l15;
                float bv = bias[col];
#pragma unroll
                for (int r = 0; r < 4; ++r)
                    vout[(size_t)col * 4096 + rowb + r] = f2bf(acc[i][j][r] + bv);
            }
        }
    }
}

// ---------------- flash attention v13: v11 with shfl_xor cross-half reduces ----------------
// All three permlane32_swap-reduce variants produced bit-identical wrong output;
// revert the pmax/psum reduce to the v7-hardware-verified __shfl_xor(.,32) idiom.
// Retained from the VALU-slim rework: native v_exp, f3max trees, hoisted LDS/stage
// addresses, 3-buffer ring with counted vmcnt, setprio, KV-split-2.
__global__ void __launch_bounds__(256) k_attn8(
    const unsigned short* __restrict__ qb,
    const unsigned short* __restrict__ kb,
    const unsigned short* __restrict__ vT,
    float* __restrict__ po0, float* __restrict__ po1,
    float* __restrict__ ml)
{
    // Sm shorts: K(buf) at buf*4096, V(buf) at 12288 + buf*4096  (bytes: *2)
    __shared__ __align__(16) unsigned short Sm[24576];
    __shared__ float bl[4][32];
    const int tid = threadIdx.x, lane = tid & 63, wid = tid >> 6;
    const int l31 = lane & 31, hi = lane >> 5;
    const int bh = blockIdx.y;
    const int b = bh >> 4, h = bh & 15;
    const int z = blockIdx.z;
    const int kv0 = z << 10;
    const int q0 = blockIdx.x * 128 + wid * 32;
    float* __restrict__ po = z ? po1 : po0;
    float* __restrict__ mlz = ml + (size_t)z * (32 * 2048 * 2);

    const unsigned short* qrow = qb + ((size_t)(b * S_LEN + q0 + l31)) * EMB + h * HDIM + hi * 8;
    bf8 qf[4];
#pragma unroll
    for (int c = 0; c < 4; ++c) qf[c] = *(const bf8*)(qrow + c * 16);

    // ---- hoisted ds-read per-lane byte offsets (chunk A rows; B = +4096 imm) ----
    const int mz = l31 & 7;
    const int koA0 = l31 * 128 + (((0 * 2 + hi) ^ mz) << 4);
    const int koA1 = l31 * 128 + (((1 * 2 + hi) ^ mz) << 4);
    const int koA2 = l31 * 128 + (((2 * 2 + hi) ^ mz) << 4);
    const int koA3 = l31 * 128 + (((3 * 2 + hi) ^ mz) << 4);
    const char* ldsc = (const char*)Sm;

    // ---- hoisted stage per-lane byte offsets ----
    const int srow = lane >> 3, sp = lane & 7;
    const int r0 = wid * 16 + srow,     p0s = sp ^ (r0 & 7);
    const int r1 = wid * 16 + 8 + srow, p1s = sp ^ (r1 & 7);
    const int kgo0 = (r0 * EMB + p0s * 8) * 2, kgo1 = (r1 * EMB + p1s * 8) * 2;
    const int vgo0 = (r0 * (S_LEN * BATCH) + p0s * 8) * 2, vgo1 = (r1 * (S_LEN * BATCH) + p1s * 8) * 2;

    // uniform advancing source pointers (chunk being staged)
    const unsigned short* kS = kb + ((size_t)(b * S_LEN + kv0)) * EMB + h * HDIM;
    const unsigned short* vS = vT + ((size_t)h * HDIM) * (S_LEN * BATCH) + b * S_LEN + kv0;

// dest: wave wid owns tile rows [wid*16, wid*16+16) = shorts [wid*1024, +1024)
#define STAGE8(DBUF) do { \
    gl_lds16((const unsigned short*)((const char*)kS + kgo0), Sm + (DBUF) * 4096 + wid * 1024); \
    gl_lds16((const unsigned short*)((const char*)vS + vgo0), Sm + 12288 + (DBUF) * 4096 + wid * 1024); \
    gl_lds16((const unsigned short*)((const char*)kS + kgo1), Sm + (DBUF) * 4096 + wid * 1024 + 512); \
    gl_lds16((const unsigned short*)((const char*)vS + vgo1), Sm + 12288 + (DBUF) * 4096 + wid * 1024 + 512); \
    kS += 64 * EMB; vS += 64; } while (0)

    auto pack2 = [](float lo, float hh) -> unsigned {
        unsigned short a  = __builtin_bit_cast(unsigned short, (__bf16)lo);
        unsigned short bb = __builtin_bit_cast(unsigned short, (__bf16)hh);
        return ((unsigned)bb << 16) | a;
    };

    float m_run = 0.f, l_run = 0.f;
    f32x16 oacc0 = {}, oacc1 = {};
    const f32x16 Z16 = {};

    STAGE8(0);
    STAGE8(1);

#define ABODY(BUF, DOSTG, LASTW) do { \
    if (LASTW) asm volatile("s_waitcnt vmcnt(0)" ::: "memory"); \
    else       asm volatile("s_waitcnt vmcnt(4)" ::: "memory"); \
    __builtin_amdgcn_s_barrier(); \
    if (DOSTG) STAGE8(((BUF) + 2) % 3); \
    bf8 ka0 = *(const bf8*)(ldsc + koA0 + (BUF) * 8192); \
    bf8 ka1 = *(const bf8*)(ldsc + koA1 + (BUF) * 8192); \
    bf8 ka2 = *(const bf8*)(ldsc + koA2 + (BUF) * 8192); \
    bf8 ka3 = *(const bf8*)(ldsc + koA3 + (BUF) * 8192); \
    bf8 kb0 = *(const bf8*)(ldsc + koA0 + (BUF) * 8192 + 4096); \
    bf8 kb1 = *(const bf8*)(ldsc + koA1 + (BUF) * 8192 + 4096); \
    bf8 kb2 = *(const bf8*)(ldsc + koA2 + (BUF) * 8192 + 4096); \
    bf8 kb3 = *(const bf8*)(ldsc + koA3 + (BUF) * 8192 + 4096); \
    __builtin_amdgcn_s_setprio(1); \
    f32x16 stA = __builtin_amdgcn_mfma_f32_32x32x16_bf16(ka0, qf[0], Z16, 0, 0, 0); \
    f32x16 stB = __builtin_amdgcn_mfma_f32_32x32x16_bf16(kb0, qf[0], Z16, 0, 0, 0); \
    stA = __builtin_amdgcn_mfma_f32_32x32x16_bf16(ka1, qf[1], stA, 0, 0, 0); \
    stB = __builtin_amdgcn_mfma_f32_32x32x16_bf16(kb1, qf[1], stB, 0, 0, 0); \
    stA = __builtin_amdgcn_mfma_f32_32x32x16_bf16(ka2, qf[2], stA, 0, 0, 0); \
    stB = __builtin_amdgcn_mfma_f32_32x32x16_bf16(kb2, qf[2], stB, 0, 0, 0); \
    stA = __builtin_amdgcn_mfma_f32_32x32x16_bf16(ka3, qf[3], stA, 0, 0, 0); \
    stB = __builtin_amdgcn_mfma_f32_32x32x16_bf16(kb3, qf[3], stB, 0, 0, 0); \
    __builtin_amdgcn_s_setprio(0); \
    float g0 = f3max(f3max(stA[0], stA[1], stA[2]),  f3max(stA[3], stA[4], stA[5]),  f3max(stA[6], stA[7], stA[8])); \
    float g1 = f3max(f3max(stA[9], stA[10], stA[11]), f3max(stA[12], stA[13], stA[14]), fmaxf(stA[15], stB[0])); \
    float g2 = f3max(f3max(stB[1], stB[2], stB[3]),  f3max(stB[4], stB[5], stB[6]),  f3max(stB[7], stB[8], stB[9])); \
    float g3 = f3max(f3max(stB[10], stB[11], stB[12]), f3max(stB[13], stB[14], stB[15]), fmaxf(g0, g1)); \
    float pmax = f3max(g2, g3, g0); \
    pmax = fmaxf(pmax, __shfl_xor(pmax, 32)); \
    if (!__all(pmax - m_run <= 11.54f)) { \
        float mnew = fmaxf(m_run, pmax); \
        float corr = fexp2(m_run - mnew); \
        l_run *= corr; m_run = mnew; \
        if (hi == 0) bl[wid][l31] = corr; \
        asm volatile("s_waitcnt lgkmcnt(0)" ::: "memory"); \
        _Pragma("unroll") for (int r = 0; r < 16; ++r) { \
            float c2 = bl[wid][(r & 3) + 8 * (r >> 2) + 4 * hi]; \
            oacc0[r] *= c2; oacc1[r] *= c2; } \
    } \
    float pA[16], pB[16]; \
    _Pragma("unroll") for (int r = 0; r < 16; ++r) pA[r] = fexp2(stA[r] - m_run); \
    _Pragma("unroll") for (int r = 0; r < 16; ++r) pB[r] = fexp2(stB[r] - m_run); \
    float sA = (((pA[0] + pA[1]) + (pA[2] + pA[3])) + ((pA[4] + pA[5]) + (pA[6] + pA[7]))) \
             + (((pA[8] + pA[9]) + (pA[10] + pA[11])) + ((pA[12] + pA[13]) + (pA[14] + pA[15]))); \
    float sB = (((pB[0] + pB[1]) + (pB[2] + pB[3])) + ((pB[4] + pB[5]) + (pB[6] + pB[7]))) \
             + (((pB[8] + pB[9]) + (pB[10] + pB[11])) + ((pB[12] + pB[13]) + (pB[14] + pB[15]))); \
    float psum = sA + sB; \
    psum += __shfl_xor(psum, 32); \
    l_run += psum; \
    unsigned a0w = pack2(pA[0], pA[1]),  a1w = pack2(pA[2], pA[3]); \
    unsigned a2w = pack2(pA[4], pA[5]),  a3w = pack2(pA[6], pA[7]); \
    unsigned a4w = pack2(pA[8], pA[9]),  a5w = pack2(pA[10], pA[11]); \
    unsigned a6w = pack2(pA[12], pA[13]), a7w = pack2(pA[14], pA[15]); \
    unsigned rA_ = (unsigned)__shfl_xor((int)(hi ? a0w : a2w), 32); \
    unsigned rB_ = (unsigned)__shfl_xor((int)(hi ? a1w : a3w), 32); \
    unsigned rC_ = (unsigned)__shfl_xor((int)(hi ? a4w : a6w), 32); \
    unsigned rD_ = (unsigned)__shfl_xor((int)(hi ? a5w : a7w), 32); \
    uint4 uA0 = hi ? uint4{rA_, rB_, a2w, a3w} : uint4{a0w, a1w, rA_, rB_}; \
    uint4 uA1 = hi ? uint4{rC_, rD_, a6w, a7w} : uint4{a4w, a5w, rC_, rD_}; \
    bf8 pf0A = __builtin_bit_cast(bf8, uA0); \
    bf8 pf1A = __builtin_bit_cast(bf8, uA1); \
    unsigned b0w = pack2(pB[0], pB[1]),  b1w = pack2(pB[2], pB[3]); \
    unsigned b2w = pack2(pB[4], pB[5]),  b3w = pack2(pB[6], pB[7]); \
    unsigned b4w = pack2(pB[8], pB[9]),  b5w = pack2(pB[10], pB[11]); \
    unsigned b6w = pack2(pB[12], pB[13]), b7w = pack2(pB[14], pB[15]); \
    unsigned rE_ = (unsigned)__shfl_xor((int)(hi ? b0w : b2w), 32); \
    unsigned rF_ = (unsigned)__shfl_xor((int)(hi ? b1w : b3w), 32); \
    unsigned rG_ = (unsigned)__shfl_xor((int)(hi ? b4w : b6w), 32); \
    unsigned rH_ = (unsigned)__shfl_xor((int)(hi ? b5w : b7w), 32); \
    uint4 uB0 = hi ? uint4{rE_, rF_, b2w, b3w} : uint4{b0w, b1w, rE_, rF_}; \
    uint4 uB1 = hi ? uint4{rG_, rH_, b6w, b7w} : uint4{b4w, b5w, rG_, rH_}; \
    bf8 pf0B = __builtin_bit_cast(bf8, uB0); \
    bf8 pf1B = __builtin_bit_cast(bf8, uB1); \
    bf8 va0 = *(const bf8*)(ldsc + koA0 + 24576 + (BUF) * 8192); \
    bf8 va1 = *(const bf8*)(ldsc + koA1 + 24576 + (BUF) * 8192); \
    bf8 va2 = *(const bf8*)(ldsc + koA2 + 24576 + (BUF) * 8192); \
    bf8 va3 = *(const bf8*)(ldsc + koA3 + 24576 + (BUF) * 8192); \
    bf8 vb0 = *(const bf8*)(ldsc + koA0 + 24576 + (BUF) * 8192 + 4096); \
    bf8 vb1 = *(const bf8*)(ldsc + koA1 + 24576 + (BUF) * 8192 + 4096); \
    bf8 vb2 = *(const bf8*)(ldsc + koA2 + 24576 + (BUF) * 8192 + 4096); \
    bf8 vb3 = *(const bf8*)(ldsc + koA3 + 24576 + (BUF) * 8192 + 4096); \
    __builtin_amdgcn_s_setprio(1); \
    oacc0 = __builtin_amdgcn_mfma_f32_32x32x16_bf16(pf0A, va0, oacc0, 0, 0, 0); \
    oacc1 = __builtin_amdgcn_mfma_f32_32x32x16_bf16(pf0A, vb0, oacc1, 0, 0, 0); \
    oacc0 = __builtin_amdgcn_mfma_f32_32x32x16_bf16(pf1A, va1, oacc0, 0, 0, 0); \
    oacc1 = __builtin_amdgcn_mfma_f32_32x32x16_bf16(pf1A, vb1, oacc1, 0, 0, 0); \
    oacc0 = __builtin_amdgcn_mfma_f32_32x32x16_bf16(pf0B, va2, oacc0, 0, 0, 0); \
    oacc1 = __builtin_amdgcn_mfma_f32_32x32x16_bf16(pf0B, vb2, oacc1, 0, 0, 0); \
    oacc0 = __builtin_amdgcn_mfma_f32_32x32x16_bf16(pf1B, va3, oacc0, 0, 0, 0); \
    oacc1 = __builtin_amdgcn_mfma_f32_32x32x16_bf16(pf1B, vb3, oacc1, 0, 0, 0); \
    __builtin_amdgcn_s_setprio(0); \
} while (0)

    // 16 chunks: 5 x (buf 0,1,2) + tail (buf 0)
    for (int t3 = 0; t3 < 5; ++t3) {
        ABODY(0, true, false);
        ABODY(1, true, false);
        ABODY(2, (t3 < 4), false);
    }
    ABODY(0, false, true);

#undef ABODY
#undef STAGE8

    // ---- epilogue: store unnormalized fp32 partial O + (m,l) ----
#pragma unroll
    for (int r = 0; r < 16; ++r) {
        int q = (r & 3) + 8 * (r >> 2) + 4 * hi;
        size_t base = ((size_t)bh * 2048 + q0 + q) * 64 + l31;
        po[base]      = oacc0[r];
        po[base + 32] = oacc1[r];
    }
    if (hi == 0) {
        size_t mi = ((size_t)bh * 2048 + q0 + l31) * 2;
        mlz[mi]     = m_run;
        mlz[mi + 1] = l_run;
    }
}

// ---------------- combine the two KV halves -> ob bf16 [B,S,E] ----------------
__global__ void k_comb(const float* __restrict__ po0, const float* __restrict__ po1,
                       const float* __restrict__ ml, unsigned short* __restrict__ ob)
{
    int id = blockIdx.x * 256 + threadIdx.x;    // 32*2048*16 = 1048576
    int d4 = (id & 15) * 4;
    int q  = (id >> 4) & 2047;
    int bh = id >> 15;
    int b = bh >> 4, h = bh & 15;
    size_t mi = ((size_t)bh * 2048 + q) * 2;
    float m0 = ml[mi], l0 = ml[mi + 1];
    float m1 = ml[mi + (size_t)32 * 2048 * 2], l1 = ml[mi + (size_t)32 * 2048 * 2 + 1];
    float m = fmaxf(m0, m1);
    float w0 = fexp2(m0 - m), w1 = fexp2(m1 - m);
    float inv = 1.0f / (l0 * w0 + l1 * w1);
    size_t pi = ((size_t)bh * 2048 + q) * 64 + d4;
    float4 a = *(const float4*)&po0[pi];
    float4 c = *(const float4*)&po1[pi];
    ushort4 o;
    o.x = f2bf((a.x * w0 + c.x * w1) * inv);
    o.y = f2bf((a.y * w0 + c.y * w1) * inv);
    o.z = f2bf((a.z * w0 + c.z * w1) * inv);
    o.w = f2bf((a.w * w0 + c.w * w1) * inv);
    *(ushort4*)&ob[((size_t)(b * S_LEN + q)) * EMB + h * HDIM + d4] = o;
}

// ---------------- final GEMM (out fp32, row remap) ----------------
template<int EPI, typename OutT>
__global__ void __launch_bounds__(256) k_gemm(
    const unsigned short* __restrict__ A,
    const unsigned short* __restrict__ B,
    const float* __restrict__ bias,
    OutT* __restrict__ C,
    int M, int N, int K)
{
    __shared__ __align__(16) unsigned short As[128 * 32];
    __shared__ __align__(16) unsigned short Bs[128 * 32];
    const int tid  = threadIdx.x;
    const int lane = tid & 63;
    const int wid  = tid >> 6;
    const int wm = wid >> 1, wn = wid & 1;
    const int l15 = lane & 15, lh = lane >> 4;
    const int tm0 = blockIdx.y * 128, tn0 = blockIdx.x * 128;

    f32x4 acc[4][4] = {};

    for (int k0 = 0; k0 < K; k0 += 32) {
        __syncthreads();
#pragma unroll
        for (int rnd = 0; rnd < 2; ++rnd) {
            int cbase = wid * 64 + rnd * 256;
            int c = cbase + lane;
            int row = c >> 2, co = (c & 3) * 8;
            gl_lds16(A + (size_t)(tm0 + row) * K + k0 + co, &As[cbase * 8]);
            gl_lds16(B + (size_t)(tn0 + row) * K + k0 + co, &Bs[cbase * 8]);
        }
        __syncthreads();
        bf8 a[4], b[4];
#pragma unroll
        for (int i = 0; i < 4; ++i) {
            a[i] = *(const bf8*)&As[(wm * 64 + i * 16 + l15) * 32 + lh * 8];
            b[i] = *(const bf8*)&Bs[(wn * 64 + i * 16 + l15) * 32 + lh * 8];
        }
#pragma unroll
        for (int i = 0; i < 4; ++i)
#pragma unroll
            for (int j = 0; j < 4; ++j)
                acc[i][j] = __builtin_amdgcn_mfma_f32_16x16x32_bf16(a[i], b[j], acc[i][j], 0, 0, 0);
    }

#pragma unroll
    for (int i = 0; i < 4; ++i) {
        const int rowb = tm0 + wm * 64 + i * 16 + lh * 4;
#pragma unroll
        for (int j = 0; j < 4; ++j) {
            const int col = tn0 + wn * 64 + j * 16 + l15;
#pragma unroll
            for (int r = 0; r < 4; ++r) {
                float v = acc[i][j][r];
                int row = rowb + r;
                if (EPI == 0) {
                    v += bias[col];
                    C[(size_t)row * N + col] = (OutT)f2bf(v);
                } else {
                    v += bias[col];
                    int bb = row >> 11, ss = row & 2047;
                    ((float*)C)[(size_t)(ss * BATCH + bb) * N + col] = v;
                }
            }
        }
    }
}

extern "C" void kernel_launch(void* const* d_in, const int* in_sizes, int n_in,
                              void* d_out, int out_size, void* d_ws, size_t ws_size,
                              hipStream_t stream)
{
    (void)in_sizes; (void)n_in; (void)out_size; (void)ws_size;
    const float* query = (const float*)d_in[0];
    const float* wq = (const float*)d_in[1];
    const float* bq = (const float*)d_in[2];
    const float* wk = (const float*)d_in[3];
    const float* bk = (const float*)d_in[4];
    const float* wv = (const float*)d_in[5];
    const float* bv = (const float*)d_in[6];
    const float* wo = (const float*)d_in[7];
    const float* bo = (const float*)d_in[8];

    // ws layout, 59 MB peak:
    //  [0,1)    cosT/sinT  -> later ml
    //  [1,17)   xb/wqb/wkb/wvb -> later po0 fp32
    //  [17,25)  qb -> later ob
    //  [25,33)  kb
    //  [33,41)  vT
    //  [41,57)  po1 fp32
    //  [57,59)  wob
    char* ws = (char*)d_ws;
    float*          cosT = (float*)(ws + 0);
    float*          sinT = (float*)(ws + (512 << 10));
    float*          ml   = (float*)(ws + 0);
    unsigned short* xb   = (unsigned short*)(ws + (1  << 20));
    float*          po0  = (float*)(ws + (1  << 20));
    unsigned short* wqb  = (unsigned short*)(ws + (9  << 20));
    unsigned short* wkb  = (unsigned short*)(ws + (11 << 20));
    unsigned short* wvb  = (unsigned short*)(ws + (13 << 20));
    unsigned short* qb   = (unsigned short*)(ws + (17 << 20));
    unsigned short* ob   = qb;                                  // time-shared
    unsigned short* kb   = (unsigned short*)(ws + (25 << 20));
    unsigned short* vT   = (unsigned short*)(ws + (33 << 20));
    float*          po1  = (float*)(ws + (41 << 20));
    unsigned short* wob  = (unsigned short*)(ws + (57 << 20));

    k_tables<<<512, 256, 0, stream>>>(cosT, sinT);
    k_cast_x<<<4096, 256, 0, stream>>>(query, xb);
    k_castW<<<4096, 256, 0, stream>>>(wq, wk, wv, wo, wqb, wkb, wvb, wob);

    dim3 gq(EMB / 128, (S_LEN * BATCH) / 128, 3);    // (8, 32, 3)
    k_gemmQKV<<<gq, 256, 0, stream>>>(xb, wqb, wkb, wvb, bq, bk, bv,
                                      qb, kb, vT, cosT, sinT);

    dim3 g3(S_LEN / 128, BATCH * NHEAD, 2);          // (16, 32, 2)
    k_attn8<<<g3, 256, 0, stream>>>(qb, kb, vT, po0, po1, ml);
    k_comb<<<4096, 256, 0, stream>>>(po0, po1, ml, ob);

    dim3 g1(EMB / 128, (S_LEN * BATCH) / 128);       // (8, 32)
    k_gemm<1, float><<<g1, 256, 0, stream>>>(ob, wob, bo, (float*)d_out, 4096, 1024, 1024);
}

// Round 14
// 153.831 us; speedup vs baseline: 1.2058x; 1.0920x over previous
//
#include <hip/hip_runtime.h>
#include <stdint.h>

#define S_LEN 2048
#define BATCH 2
#define EMB   1024
#define NHEAD 16
#define HDIM  64

typedef __bf16 bf8   __attribute__((ext_vector_type(8)));
typedef float  f32x4 __attribute__((ext_vector_type(4)));
typedef float  f32x16 __attribute__((ext_vector_type(16)));

__device__ __forceinline__ unsigned short f2bf(float f) {
    unsigned u = __builtin_bit_cast(unsigned, f);
    u += 0x7fffu + ((u >> 16) & 1u);          // round-to-nearest-even
    return (unsigned short)(u >> 16);
}
__device__ __forceinline__ float bf2f(unsigned short h) {
    unsigned u = ((unsigned)h) << 16;
    return __builtin_bit_cast(float, u);
}
__device__ __forceinline__ float fexp2(float x) { return __builtin_amdgcn_exp2f(x); }
__device__ __forceinline__ float f3max(float a, float b, float c) { return fmaxf(fmaxf(a, b), c); }

__device__ __forceinline__ void gl_lds16(const unsigned short* g, unsigned short* l) {
    __builtin_amdgcn_global_load_lds(
        (__attribute__((address_space(1))) void*)(void*)g,
        (__attribute__((address_space(3))) void*)(void*)l, 16, 0, 0);
}

// ---------------- fused prologue: rope tables + x cast + 4 weight casts ----------------
// grid 8704 x 256: [0,512) tables, [512,4608) cast_x, [4608,8704) castW
__global__ void k_prep(const float* __restrict__ x,
                       const float* __restrict__ w0, const float* __restrict__ w1,
                       const float* __restrict__ w2, const float* __restrict__ w3,
                       float* __restrict__ cosT, float* __restrict__ sinT,
                       unsigned short* __restrict__ xb,
                       unsigned short* __restrict__ o0, unsigned short* __restrict__ o1,
                       unsigned short* __restrict__ o2, unsigned short* __restrict__ o3)
{
    int bid = blockIdx.x;
    if (bid < 512) {
        int idx = bid * 256 + threadIdx.x;      // 2048*64 = 131072
        int s = idx >> 6, d = idx & 63, j = d & 31;
        float inv = exp2f(-13.28771237954945f * ((float)j * (1.0f / 32.0f)));
        float ang = (float)s * inv;
        cosT[idx] = cosf(ang);
        sinT[idx] = sinf(ang);
    } else if (bid < 4608) {
        int id = (bid - 512) * 256 + threadIdx.x;   // 1048576
        int b = id >> 19, rem = id & 524287;
        int s = rem >> 8, e4 = (rem & 255) << 2;
        float4 v = *(const float4*)&x[((size_t)(s * BATCH + b)) * EMB + e4];
        ushort4 o;
        o.x = f2bf(v.x); o.y = f2bf(v.y); o.z = f2bf(v.z); o.w = f2bf(v.w);
        *(ushort4*)&xb[((size_t)(b * S_LEN + s)) * EMB + e4] = o;
    } else {
        int id = (bid - 4608) * 256 + threadIdx.x;  // 1048576
        int seg = id >> 18, r = id & 262143;
        const float* s = seg == 0 ? w0 : seg == 1 ? w1 : seg == 2 ? w2 : w3;
        unsigned short* o = seg == 0 ? o0 : seg == 1 ? o1 : seg == 2 ? o2 : o3;
        float4 v = *(const float4*)&s[(size_t)r * 4];
        ushort4 u;
        u.x = f2bf(v.x); u.y = f2bf(v.y); u.z = f2bf(v.z); u.w = f2bf(v.w);
        *(ushort4*)&o[(size_t)r * 4] = u;
    }
}

// ---------------- merged QKV GEMM, rope fused into q/k epilogues ----------------
__global__ void __launch_bounds__(256) k_gemmQKV(
    const unsigned short* __restrict__ A,
    const unsigned short* __restrict__ Wq, const unsigned short* __restrict__ Wk,
    const unsigned short* __restrict__ Wv,
    const float* __restrict__ bqp, const float* __restrict__ bkp, const float* __restrict__ bvp,
    unsigned short* __restrict__ qout, unsigned short* __restrict__ kout,
    unsigned short* __restrict__ vout,
    const float* __restrict__ cosT, const float* __restrict__ sinT)
{
    __shared__ __align__(16) unsigned short As[128 * 32];
    __shared__ __align__(16) unsigned short Bs[128 * 32];
    const int z = blockIdx.z;
    const unsigned short* B = z == 0 ? Wq : z == 1 ? Wk : Wv;
    const float* bias = z == 0 ? bqp : z == 1 ? bkp : bvp;
    const int tid  = threadIdx.x;
    const int lane = tid & 63;
    const int wid  = tid >> 6;
    const int wm = wid >> 1, wn = wid & 1;
    const int l15 = lane & 15, lh = lane >> 4;
    const int tm0 = blockIdx.y * 128, tn0 = blockIdx.x * 128;
    const int K = 1024;

    f32x4 acc[4][4] = {};

    for (int k0 = 0; k0 < K; k0 += 32) {
        __syncthreads();
#pragma unroll
        for (int rnd = 0; rnd < 2; ++rnd) {
            int cbase = wid * 64 + rnd * 256;          // wave-uniform chunk base
            int c = cbase + lane;
            int row = c >> 2, co = (c & 3) * 8;
            gl_lds16(A + (size_t)(tm0 + row) * K + k0 + co, &As[cbase * 8]);
            gl_lds16(B + (size_t)(tn0 + row) * K + k0 + co, &Bs[cbase * 8]);
        }
        __syncthreads();
        bf8 a[4], b[4];
#pragma unroll
        for (int i = 0; i < 4; ++i) {
            a[i] = *(const bf8*)&As[(wm * 64 + i * 16 + l15) * 32 + lh * 8];
            b[i] = *(const bf8*)&Bs[(wn * 64 + i * 16 + l15) * 32 + lh * 8];
        }
#pragma unroll
        for (int i = 0; i < 4; ++i)
#pragma unroll
            for (int j = 0; j < 4; ++j)
                acc[i][j] = __builtin_amdgcn_mfma_f32_16x16x32_bf16(a[i], b[j], acc[i][j], 0, 0, 0);
    }

    if (z < 2) {
        unsigned short* C = z ? kout : qout;
        const float f = z ? 1.0f : 0.125f * 1.44269504089f;
#pragma unroll
        for (int i = 0; i < 4; ++i) {
            const int rowb = tm0 + wm * 64 + i * 16 + lh * 4;
#pragma unroll
            for (int j = 0; j < 2; ++j) {
                const int col = tn0 + wn * 64 + j * 16 + l15;   // d = j*16+l15 in [0,32)
                const int d = j * 16 + l15;
#pragma unroll
                for (int r = 0; r < 4; ++r) {
                    int m = rowb + r;
                    int sq = m & (S_LEN - 1);
                    float x1 = acc[i][j][r]     + bias[col];
                    float x2 = acc[i][j + 2][r] + bias[col + 32];
                    float c  = cosT[sq * 64 + d] * f;
                    float sn = sinT[sq * 64 + d] * f;
                    C[(size_t)m * EMB + col]      = f2bf(x1 * c - x2 * sn);
                    C[(size_t)m * EMB + col + 32] = f2bf(x2 * c + x1 * sn);
                }
            }
        }
    } else {
#pragma unroll
        for (int i = 0; i < 4; ++i) {
            const int rowb = tm0 + wm * 64 + i * 16 + lh * 4;
#pragma unroll
            for (int j = 0; j < 4; ++j) {
                const int col = tn0 + wn * 64 + j * 16 + l15;
                float bv = bias[col];
#pragma unroll
                for (int r = 0; r < 4; ++r)
                    vout[(size_t)col * 4096 + rowb + r] = f2bf(acc[i][j][r] + bv);
            }
        }
    }
}

// ---------------- flash attention v14: single-pass (split-2 reverted), normalized write ----------------
// grid: (S/128, B*H). 3-buffer LDS ring, counted vmcnt, swapped-QK 32x32,
// in-reg softmax (native v_exp), shfl_xor reduces+P-exchange (HW-verified).
// 32 chunks of 64 KV. Epilogue normalizes via bl[] broadcast, writes bf16 ob.
__global__ void __launch_bounds__(256) k_attn8(
    const unsigned short* __restrict__ qb,
    const unsigned short* __restrict__ kb,
    const unsigned short* __restrict__ vT,
    unsigned short* __restrict__ ob)
{
    // Sm shorts: K(buf) at buf*4096, V(buf) at 12288 + buf*4096  (bytes: *2)
    __shared__ __align__(16) unsigned short Sm[24576];
    __shared__ float bl[4][32];
    const int tid = threadIdx.x, lane = tid & 63, wid = tid >> 6;
    const int l31 = lane & 31, hi = lane >> 5;
    const int bh = blockIdx.y;
    const int b = bh >> 4, h = bh & 15;
    const int q0 = blockIdx.x * 128 + wid * 32;

    const unsigned short* qrow = qb + ((size_t)(b * S_LEN + q0 + l31)) * EMB + h * HDIM + hi * 8;
    bf8 qf[4];
#pragma unroll
    for (int c = 0; c < 4; ++c) qf[c] = *(const bf8*)(qrow + c * 16);

    // ---- hoisted ds-read per-lane byte offsets (chunk A rows; B = +4096 imm) ----
    const int mz = l31 & 7;
    const int koA0 = l31 * 128 + (((0 * 2 + hi) ^ mz) << 4);
    const int koA1 = l31 * 128 + (((1 * 2 + hi) ^ mz) << 4);
    const int koA2 = l31 * 128 + (((2 * 2 + hi) ^ mz) << 4);
    const int koA3 = l31 * 128 + (((3 * 2 + hi) ^ mz) << 4);
    const char* ldsc = (const char*)Sm;

    // ---- hoisted stage per-lane byte offsets ----
    const int srow = lane >> 3, sp = lane & 7;
    const int r0 = wid * 16 + srow,     p0s = sp ^ (r0 & 7);
    const int r1 = wid * 16 + 8 + srow, p1s = sp ^ (r1 & 7);
    const int kgo0 = (r0 * EMB + p0s * 8) * 2, kgo1 = (r1 * EMB + p1s * 8) * 2;
    const int vgo0 = (r0 * (S_LEN * BATCH) + p0s * 8) * 2, vgo1 = (r1 * (S_LEN * BATCH) + p1s * 8) * 2;

    // uniform advancing source pointers (chunk being staged)
    const unsigned short* kS = kb + ((size_t)(b * S_LEN)) * EMB + h * HDIM;
    const unsigned short* vS = vT + ((size_t)h * HDIM) * (S_LEN * BATCH) + b * S_LEN;

// dest: wave wid owns tile rows [wid*16, wid*16+16) = shorts [wid*1024, +1024)
#define STAGE8(DBUF) do { \
    gl_lds16((const unsigned short*)((const char*)kS + kgo0), Sm + (DBUF) * 4096 + wid * 1024); \
    gl_lds16((const unsigned short*)((const char*)vS + vgo0), Sm + 12288 + (DBUF) * 4096 + wid * 1024); \
    gl_lds16((const unsigned short*)((const char*)kS + kgo1), Sm + (DBUF) * 4096 + wid * 1024 + 512); \
    gl_lds16((const unsigned short*)((const char*)vS + vgo1), Sm + 12288 + (DBUF) * 4096 + wid * 1024 + 512); \
    kS += 64 * EMB; vS += 64; } while (0)

    auto pack2 = [](float lo, float hh) -> unsigned {
        unsigned short a  = __builtin_bit_cast(unsigned short, (__bf16)lo);
        unsigned short bb = __builtin_bit_cast(unsigned short, (__bf16)hh);
        return ((unsigned)bb << 16) | a;
    };

    float m_run = 0.f, l_run = 0.f;
    f32x16 oacc0 = {}, oacc1 = {};
    const f32x16 Z16 = {};

    STAGE8(0);
    STAGE8(1);

#define ABODY(BUF, DOSTG, LASTW) do { \
    if (LASTW) asm volatile("s_waitcnt vmcnt(0)" ::: "memory"); \
    else       asm volatile("s_waitcnt vmcnt(4)" ::: "memory"); \
    __builtin_amdgcn_s_barrier(); \
    if (DOSTG) STAGE8(((BUF) + 2) % 3); \
    bf8 ka0 = *(const bf8*)(ldsc + koA0 + (BUF) * 8192); \
    bf8 ka1 = *(const bf8*)(ldsc + koA1 + (BUF) * 8192); \
    bf8 ka2 = *(const bf8*)(ldsc + koA2 + (BUF) * 8192); \
    bf8 ka3 = *(const bf8*)(ldsc + koA3 + (BUF) * 8192); \
    bf8 kb0 = *(const bf8*)(ldsc + koA0 + (BUF) * 8192 + 4096); \
    bf8 kb1 = *(const bf8*)(ldsc + koA1 + (BUF) * 8192 + 4096); \
    bf8 kb2 = *(const bf8*)(ldsc + koA2 + (BUF) * 8192 + 4096); \
    bf8 kb3 = *(const bf8*)(ldsc + koA3 + (BUF) * 8192 + 4096); \
    __builtin_amdgcn_s_setprio(1); \
    f32x16 stA = __builtin_amdgcn_mfma_f32_32x32x16_bf16(ka0, qf[0], Z16, 0, 0, 0); \
    f32x16 stB = __builtin_amdgcn_mfma_f32_32x32x16_bf16(kb0, qf[0], Z16, 0, 0, 0); \
    stA = __builtin_amdgcn_mfma_f32_32x32x16_bf16(ka1, qf[1], stA, 0, 0, 0); \
    stB = __builtin_amdgcn_mfma_f32_32x32x16_bf16(kb1, qf[1], stB, 0, 0, 0); \
    stA = __builtin_amdgcn_mfma_f32_32x32x16_bf16(ka2, qf[2], stA, 0, 0, 0); \
    stB = __builtin_amdgcn_mfma_f32_32x32x16_bf16(kb2, qf[2], stB, 0, 0, 0); \
    stA = __builtin_amdgcn_mfma_f32_32x32x16_bf16(ka3, qf[3], stA, 0, 0, 0); \
    stB = __builtin_amdgcn_mfma_f32_32x32x16_bf16(kb3, qf[3], stB, 0, 0, 0); \
    __builtin_amdgcn_s_setprio(0); \
    float g0 = f3max(f3max(stA[0], stA[1], stA[2]),  f3max(stA[3], stA[4], stA[5]),  f3max(stA[6], stA[7], stA[8])); \
    float g1 = f3max(f3max(stA[9], stA[10], stA[11]), f3max(stA[12], stA[13], stA[14]), fmaxf(stA[15], stB[0])); \
    float g2 = f3max(f3max(stB[1], stB[2], stB[3]),  f3max(stB[4], stB[5], stB[6]),  f3max(stB[7], stB[8], stB[9])); \
    float g3 = f3max(f3max(stB[10], stB[11], stB[12]), f3max(stB[13], stB[14], stB[15]), fmaxf(g0, g1)); \
    float pmax = f3max(g2, g3, g0); \
    pmax = fmaxf(pmax, __shfl_xor(pmax, 32)); \
    if (!__all(pmax - m_run <= 11.54f)) { \
        float mnew = fmaxf(m_run, pmax); \
        float corr = fexp2(m_run - mnew); \
        l_run *= corr; m_run = mnew; \
        if (hi == 0) bl[wid][l31] = corr; \
        asm volatile("s_waitcnt lgkmcnt(0)" ::: "memory"); \
        _Pragma("unroll") for (int r = 0; r < 16; ++r) { \
            float c2 = bl[wid][(r & 3) + 8 * (r >> 2) + 4 * hi]; \
            oacc0[r] *= c2; oacc1[r] *= c2; } \
    } \
    float pA[16], pB[16]; \
    _Pragma("unroll") for (int r = 0; r < 16; ++r) pA[r] = fexp2(stA[r] - m_run); \
    _Pragma("unroll") for (int r = 0; r < 16; ++r) pB[r] = fexp2(stB[r] - m_run); \
    float sA = (((pA[0] + pA[1]) + (pA[2] + pA[3])) + ((pA[4] + pA[5]) + (pA[6] + pA[7]))) \
             + (((pA[8] + pA[9]) + (pA[10] + pA[11])) + ((pA[12] + pA[13]) + (pA[14] + pA[15]))); \
    float sB = (((pB[0] + pB[1]) + (pB[2] + pB[3])) + ((pB[4] + pB[5]) + (pB[6] + pB[7]))) \
             + (((pB[8] + pB[9]) + (pB[10] + pB[11])) + ((pB[12] + pB[13]) + (pB[14] + pB[15]))); \
    float psum = sA + sB; \
    psum += __shfl_xor(psum, 32); \
    l_run += psum; \
    unsigned a0w = pack2(pA[0], pA[1]),  a1w = pack2(pA[2], pA[3]); \
    unsigned a2w = pack2(pA[4], pA[5]),  a3w = pack2(pA[6], pA[7]); \
    unsigned a4w = pack2(pA[8], pA[9]),  a5w = pack2(pA[10], pA[11]); \
    unsigned a6w = pack2(pA[12], pA[13]), a7w = pack2(pA[14], pA[15]); \
    unsigned rA_ = (unsigned)__shfl_xor((int)(hi ? a0w : a2w), 32); \
    unsigned rB_ = (unsigned)__shfl_xor((int)(hi ? a1w : a3w), 32); \
    unsigned rC_ = (unsigned)__shfl_xor((int)(hi ? a4w : a6w), 32); \
    unsigned rD_ = (unsigned)__shfl_xor((int)(hi ? a5w : a7w), 32); \
    uint4 uA0 = hi ? uint4{rA_, rB_, a2w, a3w} : uint4{a0w, a1w, rA_, rB_}; \
    uint4 uA1 = hi ? uint4{rC_, rD_, a6w, a7w} : uint4{a4w, a5w, rC_, rD_}; \
    bf8 pf0A = __builtin_bit_cast(bf8, uA0); \
    bf8 pf1A = __builtin_bit_cast(bf8, uA1); \
    unsigned b0w = pack2(pB[0], pB[1]),  b1w = pack2(pB[2], pB[3]); \
    unsigned b2w = pack2(pB[4], pB[5]),  b3w = pack2(pB[6], pB[7]); \
    unsigned b4w = pack2(pB[8], pB[9]),  b5w = pack2(pB[10], pB[11]); \
    unsigned b6w = pack2(pB[12], pB[13]), b7w = pack2(pB[14], pB[15]); \
    unsigned rE_ = (unsigned)__shfl_xor((int)(hi ? b0w : b2w), 32); \
    unsigned rF_ = (unsigned)__shfl_xor((int)(hi ? b1w : b3w), 32); \
    unsigned rG_ = (unsigned)__shfl_xor((int)(hi ? b4w : b6w), 32); \
    unsigned rH_ = (unsigned)__shfl_xor((int)(hi ? b5w : b7w), 32); \
    uint4 uB0 = hi ? uint4{rE_, rF_, b2w, b3w} : uint4{b0w, b1w, rE_, rF_}; \
    uint4 uB1 = hi ? uint4{rG_, rH_, b6w, b7w} : uint4{b4w, b5w, rG_, rH_}; \
    bf8 pf0B = __builtin_bit_cast(bf8, uB0); \
    bf8 pf1B = __builtin_bit_cast(bf8, uB1); \
    bf8 va0 = *(const bf8*)(ldsc + koA0 + 24576 + (BUF) * 8192); \
    bf8 va1 = *(const bf8*)(ldsc + koA1 + 24576 + (BUF) * 8192); \
    bf8 va2 = *(const bf8*)(ldsc + koA2 + 24576 + (BUF) * 8192); \
    bf8 va3 = *(const bf8*)(ldsc + koA3 + 24576 + (BUF) * 8192); \
    bf8 vb0 = *(const bf8*)(ldsc + koA0 + 24576 + (BUF) * 8192 + 4096); \
    bf8 vb1 = *(const bf8*)(ldsc + koA1 + 24576 + (BUF) * 8192 + 4096); \
    bf8 vb2 = *(const bf8*)(ldsc + koA2 + 24576 + (BUF) * 8192 + 4096); \
    bf8 vb3 = *(const bf8*)(ldsc + koA3 + 24576 + (BUF) * 8192 + 4096); \
    __builtin_amdgcn_s_setprio(1); \
    oacc0 = __builtin_amdgcn_mfma_f32_32x32x16_bf16(pf0A, va0, oacc0, 0, 0, 0); \
    oacc1 = __builtin_amdgcn_mfma_f32_32x32x16_bf16(pf0A, vb0, oacc1, 0, 0, 0); \
    oacc0 = __builtin_amdgcn_mfma_f32_32x32x16_bf16(pf1A, va1, oacc0, 0, 0, 0); \
    oacc1 = __builtin_amdgcn_mfma_f32_32x32x16_bf16(pf1A, vb1, oacc1, 0, 0, 0); \
    oacc0 = __builtin_amdgcn_mfma_f32_32x32x16_bf16(pf0B, va2, oacc0, 0, 0, 0); \
    oacc1 = __builtin_amdgcn_mfma_f32_32x32x16_bf16(pf0B, vb2, oacc1, 0, 0, 0); \
    oacc0 = __builtin_amdgcn_mfma_f32_32x32x16_bf16(pf1B, va3, oacc0, 0, 0, 0); \
    oacc1 = __builtin_amdgcn_mfma_f32_32x32x16_bf16(pf1B, vb3, oacc1, 0, 0, 0); \
    __builtin_amdgcn_s_setprio(0); \
} while (0)

    // 32 chunks: 10 x (buf 0,1,2) + tails (buf 0, buf 1)
    for (int t3 = 0; t3 < 10; ++t3) {
        ABODY(0, true, false);
        ABODY(1, true, false);
        ABODY(2, true, false);
    }
    ABODY(0, false, false);
    ABODY(1, false, true);

#undef ABODY
#undef STAGE8

    // ---- epilogue: broadcast denominators, normalize, store bf16 ----
    if (hi == 0) bl[wid][l31] = l_run;
    asm volatile("s_waitcnt lgkmcnt(0)" ::: "memory");
#pragma unroll
    for (int r = 0; r < 16; ++r) {
        int q = (r & 3) + 8 * (r >> 2) + 4 * hi;
        float linv = 1.0f / bl[wid][q];
        size_t base = ((size_t)(b * S_LEN + q0 + q)) * EMB + h * HDIM + l31;
        ob[base]      = f2bf(oacc0[r] * linv);
        ob[base + 32] = f2bf(oacc1[r] * linv);
    }
}

// ---------------- final GEMM (out fp32, row remap) ----------------
template<int EPI, typename OutT>
__global__ void __launch_bounds__(256) k_gemm(
    const unsigned short* __restrict__ A,
    const unsigned short* __restrict__ B,
    const float* __restrict__ bias,
    OutT* __restrict__ C,
    int M, int N, int K)
{
    __shared__ __align__(16) unsigned short As[128 * 32];
    __shared__ __align__(16) unsigned short Bs[128 * 32];
    const int tid  = threadIdx.x;
    const int lane = tid & 63;
    const int wid  = tid >> 6;
    const int wm = wid >> 1, wn = wid & 1;
    const int l15 = lane & 15, lh = lane >> 4;
    const int tm0 = blockIdx.y * 128, tn0 = blockIdx.x * 128;

    f32x4 acc[4][4] = {};

    for (int k0 = 0; k0 < K; k0 += 32) {
        __syncthreads();
#pragma unroll
        for (int rnd = 0; rnd < 2; ++rnd) {
            int cbase = wid * 64 + rnd * 256;
            int c = cbase + lane;
            int row = c >> 2, co = (c & 3) * 8;
            gl_lds16(A + (size_t)(tm0 + row) * K + k0 + co, &As[cbase * 8]);
            gl_lds16(B + (size_t)(tn0 + row) * K + k0 + co, &Bs[cbase * 8]);
        }
        __syncthreads();
        bf8 a[4], b[4];
#pragma unroll
        for (int i = 0; i < 4; ++i) {
            a[i] = *(const bf8*)&As[(wm * 64 + i * 16 + l15) * 32 + lh * 8];
            b[i] = *(const bf8*)&Bs[(wn * 64 + i * 16 + l15) * 32 + lh * 8];
        }
#pragma unroll
        for (int i = 0; i < 4; ++i)
#pragma unroll
            for (int j = 0; j < 4; ++j)
                acc[i][j] = __builtin_amdgcn_mfma_f32_16x16x32_bf16(a[i], b[j], acc[i][j], 0, 0, 0);
    }

#pragma unroll
    for (int i = 0; i < 4; ++i) {
        const int rowb = tm0 + wm * 64 + i * 16 + lh * 4;
#pragma unroll
        for (int j = 0; j < 4; ++j) {
            const int col = tn0 + wn * 64 + j * 16 + l15;
#pragma unroll
            for (int r = 0; r < 4; ++r) {
                float v = acc[i][j][r];
                int row = rowb + r;
                if (EPI == 0) {
                    v += bias[col];
                    C[(size_t)row * N + col] = (OutT)f2bf(v);
                } else {
                    v += bias[col];
                    int bb = row >> 11, ss = row & 2047;
                    ((float*)C)[(size_t)(ss * BATCH + bb) * N + col] = v;
                }
            }
        }
    }
}

extern "C" void kernel_launch(void* const* d_in, const int* in_sizes, int n_in,
                              void* d_out, int out_size, void* d_ws, size_t ws_size,
                              hipStream_t stream)
{
    (void)in_sizes; (void)n_in; (void)out_size; (void)ws_size;
    const float* query = (const float*)d_in[0];
    const float* wq = (const float*)d_in[1];
    const float* bq = (const float*)d_in[2];
    const float* wk = (const float*)d_in[3];
    const float* bk = (const float*)d_in[4];
    const float* wv = (const float*)d_in[5];
    const float* bv = (const float*)d_in[6];
    const float* wo = (const float*)d_in[7];
    const float* bo = (const float*)d_in[8];

    // ws layout, 41 MB peak:
    //  [0,1)    cosT/sinT
    //  [1,9)    xb
    //  [9,17)   wqb/wkb/wvb/wob (2 MB each)
    //  [17,25)  qb -> ob (attn writes its own rows after reading them)
    //  [25,33)  kb
    //  [33,41)  vT
    char* ws = (char*)d_ws;
    float*          cosT = (float*)(ws + 0);
    float*          sinT = (float*)(ws + (512 << 10));
    unsigned short* xb   = (unsigned short*)(ws + (1  << 20));
    unsigned short* wqb  = (unsigned short*)(ws + (9  << 20));
    unsigned short* wkb  = (unsigned short*)(ws + (11 << 20));
    unsigned short* wvb  = (unsigned short*)(ws + (13 << 20));
    unsigned short* wob  = (unsigned short*)(ws + (15 << 20));
    unsigned short* qb   = (unsigned short*)(ws + (17 << 20));
    unsigned short* ob   = qb;                                  // time-shared
    unsigned short* kb   = (unsigned short*)(ws + (25 << 20));
    unsigned short* vT   = (unsigned short*)(ws + (33 << 20));

    k_prep<<<8704, 256, 0, stream>>>(query, wq, wk, wv, wo,
                                     cosT, sinT, xb, wqb, wkb, wvb, wob);

    dim3 gq(EMB / 128, (S_LEN * BATCH) / 128, 3);    // (8, 32, 3)
    k_gemmQKV<<<gq, 256, 0, stream>>>(xb, wqb, wkb, wvb, bq, bk, bv,
                                      qb, kb, vT, cosT, sinT);

    dim3 g3(S_LEN / 128, BATCH * NHEAD);             // (16, 32)
    k_attn8<<<g3, 256, 0, stream>>>(qb, kb, vT, ob);

    dim3 g1(EMB / 128, (S_LEN * BATCH) / 128);       // (8, 32)
    k_gemm<1, float><<<g1, 256, 0, stream>>>(ob, wob, bo, (float*)d_out, 4096, 1024, 1024);
}